// Round 7
// baseline (354.378 us; speedup 1.0000x reference)
//
#include <hip/hip_runtime.h>
#include <math.h>

#define D_MODEL 1024
#define SEQ     2048
#define BATCH   8
#define VOCAB   32000
#define PAD_ID  2

typedef float f32x4 __attribute__((ext_vector_type(4)));
typedef unsigned short u16;

// log2(10000) / 1024
#define INV_EXP_C (13.287712379549449f / 1024.0f)

// f32 -> bf16 round-to-nearest-even (finite values)
static __device__ inline u16 f2bf(float f) {
    unsigned u = __float_as_uint(f);
    return (u16)((u + 0x7FFFu + ((u >> 16) & 1u)) >> 16);
}
static __device__ inline float bf2f(u16 v) {
    return __uint_as_float(((unsigned)v) << 16);
}

// --------------------------------------------------------------------------
// PE table: pe[s][d]; d even: cos((s+1)*10000^(-d/1024));
//                     d odd : sin((s+1)*10000^(-(d+1)/1024))
// --------------------------------------------------------------------------
__global__ __launch_bounds__(256) void pe_kernel(float* __restrict__ pe) {
    const int s  = blockIdx.x;
    const int d0 = threadIdx.x * 4;
    const float pos = (float)(s + 1);

    const float inv0 = exp2f(-(float)(d0)     * INV_EXP_C);
    const float inv1 = exp2f(-(float)(d0 + 2) * INV_EXP_C);
    const float inv2 = exp2f(-(float)(d0 + 4) * INV_EXP_C);

    float s1, c1;
    sincosf(pos * inv1, &s1, &c1);

    f32x4 v;
    v.x = cosf(pos * inv0);
    v.y = s1;
    v.z = c1;
    v.w = sinf(pos * inv2);

    *(f32x4*)(pe + (size_t)s * D_MODEL + d0) = v;
}

// --------------------------------------------------------------------------
// Transpose + bias fold -> bf16: wT[v][d] = bf16(w[d][v] + bias[d])
// grid (VOCAB/64, D_MODEL/64) = (500, 16), 256 threads, LDS [64][65] f32.
// Read coalesced along v; write coalesced along d (ushort4 = 8 B/lane).
// --------------------------------------------------------------------------
__global__ __launch_bounds__(256) void transpose_bias_bf16_kernel(
        const float* __restrict__ w,
        const float* __restrict__ bias,
        u16*         __restrict__ wT) {
    __shared__ float tile[64][65];   // [d_local][v_local]
    const int v0 = blockIdx.x * 64;
    const int d0 = blockIdx.y * 64;
    const int t  = threadIdx.x;

    // read phase: coalesced along v
    {
        const int vx = (t & 15) * 4;
        const int dy = t >> 4;                    // 0..15
        #pragma unroll
        for (int i = 0; i < 64; i += 16) {
            const int d = d0 + dy + i;
            const f32x4 val = *(const f32x4*)(w + (size_t)d * VOCAB + v0 + vx);
            const float bv = bias[d];
            tile[dy + i][vx + 0] = val.x + bv;
            tile[dy + i][vx + 1] = val.y + bv;
            tile[dy + i][vx + 2] = val.z + bv;
            tile[dy + i][vx + 3] = val.w + bv;
        }
    }
    __syncthreads();
    // write phase: coalesced along d, bf16 packed
    {
        const int dx = (t & 15) * 4;
        const int vy = t >> 4;                    // 0..15
        #pragma unroll
        for (int i = 0; i < 64; i += 16) {
            ushort4 o;
            o.x = f2bf(tile[dx + 0][vy + i]);
            o.y = f2bf(tile[dx + 1][vy + i]);
            o.z = f2bf(tile[dx + 2][vy + i]);
            o.w = f2bf(tile[dx + 3][vy + i]);
            *(ushort4*)(wT + (size_t)(v0 + vy + i) * D_MODEL + d0 + dx) = o;
        }
    }
}

// --------------------------------------------------------------------------
// Embedding gather: emb[b][s][d] = f32(wT[tok][d]) + pe[s][d]
// grid (SEQ, BATCH), 256 threads, 4 d per thread.
// --------------------------------------------------------------------------
__global__ __launch_bounds__(256) void emb_gather_kernel(
        const int*   __restrict__ x,
        const u16*   __restrict__ wT,
        const float* __restrict__ pe,
        float*       __restrict__ emb) {
    const int s = blockIdx.x;
    const int b = blockIdx.y;
    const int d0 = threadIdx.x * 4;

    const int tok = x[b * SEQ + s];   // uniform per block

    const ushort4 wv = *(const ushort4*)(wT + (size_t)tok * D_MODEL + d0);
    const f32x4   pv = *(const f32x4*)(pe + (size_t)s * D_MODEL + d0);

    f32x4 o;
    o.x = bf2f(wv.x) + pv.x;
    o.y = bf2f(wv.y) + pv.y;
    o.z = bf2f(wv.z) + pv.z;
    o.w = bf2f(wv.w) + pv.w;

    __builtin_nontemporal_store(o,
        (f32x4*)(emb + ((size_t)(b * SEQ + s)) * D_MODEL + d0));
}

// --------------------------------------------------------------------------
// Mask: mask[b][i][j] = (x[b][j] == PAD_ID), identical for all i.
// grid (SEQ/8, BATCH): compute the row chunk once, store it for 8 rows.
// --------------------------------------------------------------------------
__global__ __launch_bounds__(256) void mask_kernel(const int* __restrict__ x,
                                                   float* __restrict__ mask) {
    const int i0 = blockIdx.x * 8;
    const int b  = blockIdx.y;
    const int j0 = threadIdx.x * 8;

    const int4 xi0 = *(const int4*)(x + b * SEQ + j0);
    const int4 xi1 = *(const int4*)(x + b * SEQ + j0 + 4);

    f32x4 m0, m1;
    m0.x = (xi0.x == PAD_ID) ? 1.0f : 0.0f;
    m0.y = (xi0.y == PAD_ID) ? 1.0f : 0.0f;
    m0.z = (xi0.z == PAD_ID) ? 1.0f : 0.0f;
    m0.w = (xi0.w == PAD_ID) ? 1.0f : 0.0f;
    m1.x = (xi1.x == PAD_ID) ? 1.0f : 0.0f;
    m1.y = (xi1.y == PAD_ID) ? 1.0f : 0.0f;
    m1.z = (xi1.z == PAD_ID) ? 1.0f : 0.0f;
    m1.w = (xi1.w == PAD_ID) ? 1.0f : 0.0f;

    float* mbase = mask + ((size_t)b * SEQ + i0) * SEQ + j0;
    #pragma unroll
    for (int r = 0; r < 8; ++r) {
        __builtin_nontemporal_store(m0, (f32x4*)(mbase + (size_t)r * SEQ));
        __builtin_nontemporal_store(m1, (f32x4*)(mbase + (size_t)r * SEQ + 4));
    }
}

// --------------------------------------------------------------------------
// Fallback (tiny ws): direct strided gather + inline trig + mask.
// --------------------------------------------------------------------------
__global__ __launch_bounds__(256) void fallback_kernel(
        const int* __restrict__ x, const float* __restrict__ w,
        const float* __restrict__ bias, float* __restrict__ emb,
        float* __restrict__ mask) {
    const int s = blockIdx.x, b = blockIdx.y, t = threadIdx.x;
    const int tok = x[b * SEQ + s];
    const int d0 = t * 4;

    const float* wc = w + tok;
    const f32x4 bv = *(const f32x4*)(bias + d0);
    const float pos  = (float)(s + 1);
    const float inv0 = exp2f(-(float)(d0)     * INV_EXP_C);
    const float inv1 = exp2f(-(float)(d0 + 2) * INV_EXP_C);
    const float inv2 = exp2f(-(float)(d0 + 4) * INV_EXP_C);
    float s1, c1;
    sincosf(pos * inv1, &s1, &c1);

    f32x4 o;
    o.x = wc[(size_t)(d0 + 0) * VOCAB] + bv.x + cosf(pos * inv0);
    o.y = wc[(size_t)(d0 + 1) * VOCAB] + bv.y + s1;
    o.z = wc[(size_t)(d0 + 2) * VOCAB] + bv.z + c1;
    o.w = wc[(size_t)(d0 + 3) * VOCAB] + bv.w + sinf(pos * inv2);
    __builtin_nontemporal_store(o, (f32x4*)(emb + ((size_t)(b * SEQ + s)) * D_MODEL + d0));

    const int j0 = t * 8;
    const int4 xi0 = *(const int4*)(x + b * SEQ + j0);
    const int4 xi1 = *(const int4*)(x + b * SEQ + j0 + 4);
    f32x4 m0, m1;
    m0.x = (xi0.x == PAD_ID) ? 1.0f : 0.0f;
    m0.y = (xi0.y == PAD_ID) ? 1.0f : 0.0f;
    m0.z = (xi0.z == PAD_ID) ? 1.0f : 0.0f;
    m0.w = (xi0.w == PAD_ID) ? 1.0f : 0.0f;
    m1.x = (xi1.x == PAD_ID) ? 1.0f : 0.0f;
    m1.y = (xi1.y == PAD_ID) ? 1.0f : 0.0f;
    m1.z = (xi1.z == PAD_ID) ? 1.0f : 0.0f;
    m1.w = (xi1.w == PAD_ID) ? 1.0f : 0.0f;
    float* mrow = mask + ((size_t)b * SEQ + s) * SEQ + j0;
    __builtin_nontemporal_store(m0, (f32x4*)mrow);
    __builtin_nontemporal_store(m1, (f32x4*)(mrow + 4));
}

// --------------------------------------------------------------------------
extern "C" void kernel_launch(void* const* d_in, const int* in_sizes, int n_in,
                              void* d_out, int out_size, void* d_ws, size_t ws_size,
                              hipStream_t stream) {
    const int*   x    = (const int*)d_in[0];
    const float* w    = (const float*)d_in[1];
    const float* bias = (const float*)d_in[2];

    float* emb  = (float*)d_out;                                   // [8,2048,1024]
    float* mask = (float*)d_out + (size_t)BATCH * SEQ * D_MODEL;   // [8,2048,2048]

    // ws layout: pe (f32, 8 MB, 8-B aligned) | wT (bf16, 65.5 MB)
    const size_t pe_f  = (size_t)SEQ * D_MODEL;                    // 2M floats
    const size_t wt_e  = (size_t)VOCAB * D_MODEL;                  // 32.77M u16
    const size_t need  = pe_f * 4 + wt_e * 2;

    dim3 block(256);

    if (ws_size >= need) {
        float* pe = (float*)d_ws;
        u16*   wT = (u16*)((char*)d_ws + pe_f * 4);

        pe_kernel<<<dim3(SEQ), block, 0, stream>>>(pe);
        transpose_bias_bf16_kernel<<<dim3(VOCAB / 64, D_MODEL / 64), block, 0, stream>>>(
            w, bias, wT);
        emb_gather_kernel<<<dim3(SEQ, BATCH), block, 0, stream>>>(x, wT, pe, emb);
        mask_kernel<<<dim3(SEQ / 8, BATCH), block, 0, stream>>>(x, mask);
    } else {
        fallback_kernel<<<dim3(SEQ, BATCH), block, 0, stream>>>(x, w, bias, emb, mask);
    }
}

// Round 9
// 349.159 us; speedup vs baseline: 1.0149x; 1.0149x over previous
//
#include <hip/hip_runtime.h>
#include <math.h>

#define D_MODEL 1024
#define SEQ     2048
#define BATCH   8
#define VOCAB   32000
#define PAD_ID  2
#define SPB     8   // tokens (s values) per block in the fused kernel

typedef float f32x4 __attribute__((ext_vector_type(4)));
typedef unsigned short u16;

// log2(10000) / 1024
#define INV_EXP_C (13.287712379549449f / 1024.0f)

// f32 -> bf16 round-to-nearest-even (finite values)
static __device__ inline u16 f2bf(float f) {
    unsigned u = __float_as_uint(f);
    return (u16)((u + 0x7FFFu + ((u >> 16) & 1u)) >> 16);
}
static __device__ inline float bf2f(u16 v) {
    return __uint_as_float(((unsigned)v) << 16);
}

// --------------------------------------------------------------------------
// PE table: pe[s][d]; d even: cos((s+1)*10000^(-d/1024));
//                     d odd : sin((s+1)*10000^(-(d+1)/1024))
// (formulas identical to all prior rounds -> absmax unchanged)
// --------------------------------------------------------------------------
__global__ __launch_bounds__(256) void pe_kernel(float* __restrict__ pe) {
    const int s  = blockIdx.x;
    const int d0 = threadIdx.x * 4;
    const float pos = (float)(s + 1);

    const float inv0 = exp2f(-(float)(d0)     * INV_EXP_C);
    const float inv1 = exp2f(-(float)(d0 + 2) * INV_EXP_C);
    const float inv2 = exp2f(-(float)(d0 + 4) * INV_EXP_C);

    float s1, c1;
    sincosf(pos * inv1, &s1, &c1);

    f32x4 v;
    v.x = cosf(pos * inv0);
    v.y = s1;
    v.z = c1;
    v.w = sinf(pos * inv2);

    *(f32x4*)(pe + (size_t)s * D_MODEL + d0) = v;
}

// --------------------------------------------------------------------------
// Transpose + bias fold -> bf16: wT[v][d] = bf16(w[d][v] + bias[d])
// grid (VOCAB/64, D_MODEL/64) = (500, 16), 256 threads, LDS [64][65] f32.
// --------------------------------------------------------------------------
__global__ __launch_bounds__(256) void transpose_bias_bf16_kernel(
        const float* __restrict__ w,
        const float* __restrict__ bias,
        u16*         __restrict__ wT) {
    __shared__ float tile[64][65];   // [d_local][v_local]
    const int v0 = blockIdx.x * 64;
    const int d0 = blockIdx.y * 64;
    const int t  = threadIdx.x;

    // read phase: coalesced along v
    {
        const int vx = (t & 15) * 4;
        const int dy = t >> 4;                    // 0..15
        #pragma unroll
        for (int i = 0; i < 64; i += 16) {
            const int d = d0 + dy + i;
            const f32x4 val = *(const f32x4*)(w + (size_t)d * VOCAB + v0 + vx);
            const float bv = bias[d];
            tile[dy + i][vx + 0] = val.x + bv;
            tile[dy + i][vx + 1] = val.y + bv;
            tile[dy + i][vx + 2] = val.z + bv;
            tile[dy + i][vx + 3] = val.w + bv;
        }
    }
    __syncthreads();
    // write phase: coalesced along d, bf16 packed
    {
        const int dx = (t & 15) * 4;
        const int vy = t >> 4;                    // 0..15
        #pragma unroll
        for (int i = 0; i < 64; i += 16) {
            ushort4 o;
            o.x = f2bf(tile[dx + 0][vy + i]);
            o.y = f2bf(tile[dx + 1][vy + i]);
            o.z = f2bf(tile[dx + 2][vy + i]);
            o.w = f2bf(tile[dx + 3][vy + i]);
            *(ushort4*)(wT + (size_t)(v0 + vy + i) * D_MODEL + d0 + dx) = o;
        }
    }
}

// --------------------------------------------------------------------------
// Fused gather + PE + mask. grid (SEQ/SPB, BATCH) = (256, 8), 256 threads.
// Per block: SPB consecutive s rows of one batch element.
//   emb[b][s][d]  = f32(wT[tok_s][d]) + pe[s][d]   (loop over SPB tokens)
//   mask[b][s][j] = (x[b][j] == PAD_ID)            (computed once, stored SPB x)
// --------------------------------------------------------------------------
__global__ __launch_bounds__(256) void fused_emb_mask_kernel(
        const int*   __restrict__ x,
        const u16*   __restrict__ wT,
        const float* __restrict__ pe,
        float*       __restrict__ emb,
        float*       __restrict__ mask) {
    const int s0 = blockIdx.x * SPB;
    const int b  = blockIdx.y;
    const int t  = threadIdx.x;
    const int d0 = t * 4;

    // ---- embedding rows: SPB independent iterations (ILP) ----
    #pragma unroll
    for (int k = 0; k < SPB; ++k) {
        const int s   = s0 + k;
        const int tok = x[b * SEQ + s];           // scalar broadcast, L1-hit

        const ushort4 wv = *(const ushort4*)(wT + (size_t)tok * D_MODEL + d0);
        const f32x4   pv = *(const f32x4*)(pe + (size_t)s * D_MODEL + d0);

        f32x4 o;
        o.x = bf2f(wv.x) + pv.x;
        o.y = bf2f(wv.y) + pv.y;
        o.z = bf2f(wv.z) + pv.z;
        o.w = bf2f(wv.w) + pv.w;

        __builtin_nontemporal_store(o,
            (f32x4*)(emb + ((size_t)(b * SEQ + s)) * D_MODEL + d0));
    }

    // ---- mask rows: compute this thread's j-chunk once, store SPB times ----
    const int j0 = t * 8;
    const int4 xi0 = *(const int4*)(x + b * SEQ + j0);
    const int4 xi1 = *(const int4*)(x + b * SEQ + j0 + 4);

    f32x4 m0, m1;
    m0.x = (xi0.x == PAD_ID) ? 1.0f : 0.0f;
    m0.y = (xi0.y == PAD_ID) ? 1.0f : 0.0f;
    m0.z = (xi0.z == PAD_ID) ? 1.0f : 0.0f;
    m0.w = (xi0.w == PAD_ID) ? 1.0f : 0.0f;
    m1.x = (xi1.x == PAD_ID) ? 1.0f : 0.0f;
    m1.y = (xi1.y == PAD_ID) ? 1.0f : 0.0f;
    m1.z = (xi1.z == PAD_ID) ? 1.0f : 0.0f;
    m1.w = (xi1.w == PAD_ID) ? 1.0f : 0.0f;

    float* mbase = mask + ((size_t)b * SEQ + s0) * SEQ + j0;
    #pragma unroll
    for (int r = 0; r < SPB; ++r) {
        __builtin_nontemporal_store(m0, (f32x4*)(mbase + (size_t)r * SEQ));
        __builtin_nontemporal_store(m1, (f32x4*)(mbase + (size_t)r * SEQ + 4));
    }
}

// --------------------------------------------------------------------------
// Fallback (tiny ws): direct strided gather + inline trig + mask.
// --------------------------------------------------------------------------
__global__ __launch_bounds__(256) void fallback_kernel(
        const int* __restrict__ x, const float* __restrict__ w,
        const float* __restrict__ bias, float* __restrict__ emb,
        float* __restrict__ mask) {
    const int s = blockIdx.x, b = blockIdx.y, t = threadIdx.x;
    const int tok = x[b * SEQ + s];
    const int d0 = t * 4;

    const float* wc = w + tok;
    const f32x4 bv = *(const f32x4*)(bias + d0);
    const float pos  = (float)(s + 1);
    const float inv0 = exp2f(-(float)(d0)     * INV_EXP_C);
    const float inv1 = exp2f(-(float)(d0 + 2) * INV_EXP_C);
    const float inv2 = exp2f(-(float)(d0 + 4) * INV_EXP_C);
    float s1, c1;
    sincosf(pos * inv1, &s1, &c1);

    f32x4 o;
    o.x = wc[(size_t)(d0 + 0) * VOCAB] + bv.x + cosf(pos * inv0);
    o.y = wc[(size_t)(d0 + 1) * VOCAB] + bv.y + s1;
    o.z = wc[(size_t)(d0 + 2) * VOCAB] + bv.z + c1;
    o.w = wc[(size_t)(d0 + 3) * VOCAB] + bv.w + sinf(pos * inv2);
    __builtin_nontemporal_store(o, (f32x4*)(emb + ((size_t)(b * SEQ + s)) * D_MODEL + d0));

    const int j0 = t * 8;
    const int4 xi0 = *(const int4*)(x + b * SEQ + j0);
    const int4 xi1 = *(const int4*)(x + b * SEQ + j0 + 4);
    f32x4 m0, m1;
    m0.x = (xi0.x == PAD_ID) ? 1.0f : 0.0f;
    m0.y = (xi0.y == PAD_ID) ? 1.0f : 0.0f;
    m0.z = (xi0.z == PAD_ID) ? 1.0f : 0.0f;
    m0.w = (xi0.w == PAD_ID) ? 1.0f : 0.0f;
    m1.x = (xi1.x == PAD_ID) ? 1.0f : 0.0f;
    m1.y = (xi1.y == PAD_ID) ? 1.0f : 0.0f;
    m1.z = (xi1.z == PAD_ID) ? 1.0f : 0.0f;
    m1.w = (xi1.w == PAD_ID) ? 1.0f : 0.0f;
    float* mrow = mask + ((size_t)b * SEQ + s) * SEQ + j0;
    __builtin_nontemporal_store(m0, (f32x4*)mrow);
    __builtin_nontemporal_store(m1, (f32x4*)(mrow + 4));
}

// --------------------------------------------------------------------------
extern "C" void kernel_launch(void* const* d_in, const int* in_sizes, int n_in,
                              void* d_out, int out_size, void* d_ws, size_t ws_size,
                              hipStream_t stream) {
    const int*   x    = (const int*)d_in[0];
    const float* w    = (const float*)d_in[1];
    const float* bias = (const float*)d_in[2];

    float* emb  = (float*)d_out;                                   // [8,2048,1024]
    float* mask = (float*)d_out + (size_t)BATCH * SEQ * D_MODEL;   // [8,2048,2048]

    // ws layout: pe (f32, 8 MB) | wT (bf16, 65.5 MB)
    const size_t pe_f  = (size_t)SEQ * D_MODEL;                    // 2M floats
    const size_t wt_e  = (size_t)VOCAB * D_MODEL;                  // 32.77M u16
    const size_t need  = pe_f * 4 + wt_e * 2;

    dim3 block(256);

    if (ws_size >= need) {
        float* pe = (float*)d_ws;
        u16*   wT = (u16*)((char*)d_ws + pe_f * 4);

        pe_kernel<<<dim3(SEQ), block, 0, stream>>>(pe);
        transpose_bias_bf16_kernel<<<dim3(VOCAB / 64, D_MODEL / 64), block, 0, stream>>>(
            w, bias, wT);
        fused_emb_mask_kernel<<<dim3(SEQ / SPB, BATCH), block, 0, stream>>>(
            x, wT, pe, emb, mask);
    } else {
        fallback_kernel<<<dim3(SEQ, BATCH), block, 0, stream>>>(x, w, bias, emb, mask);
    }
}